// Round 6
// baseline (452.251 us; speedup 1.0000x reference)
//
#include <hip/hip_runtime.h>
#include <math.h>

#define NN 1024
#define NE 32768
#define NEE 262144
#define CS 384
#define CZ 128
#define CG 16
#define NH 4
#define NR 64

typedef __attribute__((ext_vector_type(8))) short short8v;
typedef __attribute__((ext_vector_type(4))) float f32x4;
typedef unsigned short ushort_t;

__device__ __forceinline__ float sigmoidf_(float x) { return 1.0f / (1.0f + __expf(-x)); }

__device__ __forceinline__ ushort_t f2bf(float x) {
    union { float f; unsigned u; } v; v.f = x;
    unsigned r = v.u + 0x7fff + ((v.u >> 16) & 1);
    return (ushort_t)(r >> 16);
}
__device__ __forceinline__ float bf2f(ushort_t x) {
    union { unsigned u; float f; } v; v.u = ((unsigned)x) << 16;
    return v.f;
}

// ---------------- node projections: nl16 (bf16) [N,16], nr (f32) [N,16] ----------------
__global__ void node_proj_kernel(const float* __restrict__ nf,
                                 const float* __restrict__ Wl, const float* __restrict__ bl,
                                 const float* __restrict__ Wr, const float* __restrict__ br,
                                 ushort_t* __restrict__ nl16, float* __restrict__ nr) {
    int wave = threadIdx.x >> 6, lane = threadIdx.x & 63;
    int n = blockIdx.x * 4 + wave;
    if (lane >= 32) return;
    bool isl = lane < 16;
    int o = isl ? lane : lane - 16;
    const float* W = isl ? Wl : Wr;
    float acc = isl ? bl[o] : br[o];
    const float* x = nf + n * CS;
    for (int k = 0; k < CS; ++k) acc += x[k] * W[k * 16 + o];
    if (isl) nl16[n * 16 + o] = f2bf(acc);
    else     nr[n * 16 + o] = acc;
}

// ---------------- Tbf[n][c][i] (bf16) = sum_j nr[n,j]*W_bg[(16i+j),c] ----------------
__global__ void build_Tt_kernel(const float* __restrict__ nr, const float* __restrict__ Wbg,
                                ushort_t* __restrict__ Tbf) {
    int n = blockIdx.x;
    int t = threadIdx.x;
    int c = t & 127, i0 = t >> 7;
    __shared__ float nrs[16];
    if (t < 16) nrs[t] = nr[n * 16 + t];
    __syncthreads();
    for (int i = i0; i < 16; i += 2) {
        float acc = 0.f;
#pragma unroll
        for (int j = 0; j < 16; ++j) acc += nrs[j] * Wbg[(i * 16 + j) * 128 + c];
        Tbf[n * 2048 + c * 16 + i] = f2bf(acc);
    }
}

// ---------------- LayerNorm over 128 -> bf16 ----------------
__global__ void ln_kernel(const float* __restrict__ x, const float* __restrict__ g,
                          const float* __restrict__ b, ushort_t* __restrict__ ef) {
    int wave = threadIdx.x >> 6, lane = threadIdx.x & 63;
    int e = blockIdx.x * 4 + wave;
    int c0 = lane, c1 = lane + 64;
    float x0 = x[e * 128 + c0], x1 = x[e * 128 + c1];
    float s = x0 + x1;
#pragma unroll
    for (int m = 1; m < 64; m <<= 1) s += __shfl_xor(s, m);
    float mean = s * (1.f / 128.f);
    float d0 = x0 - mean, d1 = x1 - mean;
    float v = d0 * d0 + d1 * d1;
#pragma unroll
    for (int m = 1; m < 64; m <<= 1) v += __shfl_xor(v, m);
    v *= (1.f / 128.f);
    float inv = rsqrtf(v + 1e-5f);
    ef[e * 128 + c0] = f2bf(d0 * inv * g[c0] + b[c0]);
    ef[e * 128 + c1] = f2bf(d1 * inv * g[c1] + b[c1]);
}

// ---------------- prep weights: WcatT(bf16, col order q|og|k|v), bcat, WdbT, WoutT ----------------
__global__ void prep_w_kernel(const float* __restrict__ Wq, const float* __restrict__ bq,
                              const float* __restrict__ Wkv, const float* __restrict__ bkv,
                              const float* __restrict__ Wog, const float* __restrict__ bog,
                              const float* __restrict__ Wdb, const float* __restrict__ Wout,
                              ushort_t* __restrict__ WcatT, float* __restrict__ bcat,
                              ushort_t* __restrict__ WdbT, ushort_t* __restrict__ WoutT) {
    int idx = blockIdx.x * 256 + threadIdx.x;  // 65536 total
    int col = idx >> 7, k = idx & 127;
    float w;
    if (col < 128) w = Wq[k * 128 + col];
    else if (col < 256) w = Wog[k * 128 + (col - 128)];
    else if (col < 384) w = Wkv[k * 256 + (col - 256)];
    else w = Wkv[k * 256 + 128 + (col - 384)];
    WcatT[idx] = f2bf(w);
    if (idx < 512) {
        float bb;
        if (idx < 128) bb = bq[idx];
        else if (idx < 256) bb = bog[idx - 128];
        else if (idx < 384) bb = bkv[idx - 256];
        else bb = bkv[idx - 384 + 128];
        bcat[idx] = bb;
    }
    if (idx < 128 * 64) {
        int c = idx >> 6, r = idx & 63;
        WdbT[idx] = f2bf(Wdb[r * 128 + c]);
    }
    if (idx < 128 * 128) {
        int c = idx >> 7, kk = idx & 127;
        WoutT[idx] = f2bf(Wout[kk * 128 + c]);
    }
}

// ---------------- MFMA GEMM: [32768,128]bf16 @ [128,512] -> qog[E,256]bf16, kv[E,256]bf16 ----------------
__global__ void __launch_bounds__(256) mfma_gemm_proj(const ushort_t* __restrict__ Abf,
                                                      const ushort_t* __restrict__ Bt,
                                                      const float* __restrict__ bias,
                                                      ushort_t* __restrict__ qog,
                                                      ushort_t* __restrict__ kvo) {
    __shared__ ushort_t As[128][136];
    __shared__ ushort_t Bs[64][136];
    int t = threadIdx.x;
    int row0 = blockIdx.y * 128;
    int n0 = blockIdx.x * 64;
#pragma unroll
    for (int u = 0; u < 8; ++u) {
        int idx = t + u * 256;
        int r = idx >> 4, seg = idx & 15;
        *(short8v*)&As[r][seg * 8] = *(const short8v*)&Abf[(size_t)(row0 + r) * 128 + seg * 8];
    }
#pragma unroll
    for (int u = 0; u < 4; ++u) {
        int idx = t + u * 256;
        int r = idx >> 4, seg = idx & 15;
        *(short8v*)&Bs[r][seg * 8] = *(const short8v*)&Bt[(size_t)(n0 + r) * 128 + seg * 8];
    }
    __syncthreads();
    int lane = t & 63, w = t >> 6;
    int wr = (w >> 1) * 64, wc = (w & 1) * 32;
    int fr = lane & 15, fk = (lane >> 4) * 8;
    f32x4 acc[4][2] = {};
#pragma unroll
    for (int kk = 0; kk < 4; ++kk) {
        short8v a[4], b[2];
#pragma unroll
        for (int m = 0; m < 4; ++m) a[m] = *(const short8v*)&As[wr + m * 16 + fr][kk * 32 + fk];
#pragma unroll
        for (int n = 0; n < 2; ++n) b[n] = *(const short8v*)&Bs[wc + n * 16 + fr][kk * 32 + fk];
#pragma unroll
        for (int m = 0; m < 4; ++m)
#pragma unroll
            for (int n = 0; n < 2; ++n)
                acc[m][n] = __builtin_amdgcn_mfma_f32_16x16x32_bf16(a[m], b[n], acc[m][n], 0, 0, 0);
    }
    __syncthreads();
    ushort_t (*stage)[72] = (ushort_t(*)[72])&As[0][0];
    int orow = (lane >> 4) * 4;
#pragma unroll
    for (int m = 0; m < 4; ++m)
#pragma unroll
        for (int n = 0; n < 2; ++n) {
            int col = wc + n * 16 + fr;
            float bv = bias[n0 + col];
#pragma unroll
            for (int j = 0; j < 4; ++j)
                stage[wr + m * 16 + orow + j][col] = f2bf(acc[m][n][j] + bv);
        }
    __syncthreads();
    ushort_t* basep; int cbase;
    if (n0 < 256) { basep = qog; cbase = n0; } else { basep = kvo; cbase = n0 - 256; }
#pragma unroll
    for (int u = 0; u < 4; ++u) {
        int idx = t + u * 256;
        int r = idx >> 3, seg = idx & 7;
        *(short8v*)&basep[(size_t)(row0 + r) * 256 + cbase + seg * 8] = *(const short8v*)&stage[r][seg * 8];
    }
}

// ---------------- MFMA GEMM: out[32768,128]f32 = updg(f32->bf16) @ WoutT + b_out ----------------
__global__ void __launch_bounds__(256) mfma_gemm_out(const float* __restrict__ Af,
                                                     const ushort_t* __restrict__ Bt,
                                                     const float* __restrict__ bias,
                                                     float* __restrict__ out) {
    __shared__ ushort_t As[128][136];
    __shared__ ushort_t Bs[64][136];
    int t = threadIdx.x;
    int row0 = blockIdx.y * 128;
    int n0 = blockIdx.x * 64;
#pragma unroll
    for (int u = 0; u < 8; ++u) {
        int idx = t + u * 256;
        int r = idx >> 4, seg = idx & 15;
        float4 f0 = *(const float4*)&Af[(size_t)(row0 + r) * 128 + seg * 8];
        float4 f1 = *(const float4*)&Af[(size_t)(row0 + r) * 128 + seg * 8 + 4];
        short8v pk;
        pk[0] = (short)f2bf(f0.x); pk[1] = (short)f2bf(f0.y);
        pk[2] = (short)f2bf(f0.z); pk[3] = (short)f2bf(f0.w);
        pk[4] = (short)f2bf(f1.x); pk[5] = (short)f2bf(f1.y);
        pk[6] = (short)f2bf(f1.z); pk[7] = (short)f2bf(f1.w);
        *(short8v*)&As[r][seg * 8] = pk;
    }
#pragma unroll
    for (int u = 0; u < 4; ++u) {
        int idx = t + u * 256;
        int r = idx >> 4, seg = idx & 15;
        *(short8v*)&Bs[r][seg * 8] = *(const short8v*)&Bt[(size_t)(n0 + r) * 128 + seg * 8];
    }
    __syncthreads();
    int lane = t & 63, w = t >> 6;
    int wr = (w >> 1) * 64, wc = (w & 1) * 32;
    int fr = lane & 15, fk = (lane >> 4) * 8;
    f32x4 acc[4][2] = {};
#pragma unroll
    for (int kk = 0; kk < 4; ++kk) {
        short8v a[4], b[2];
#pragma unroll
        for (int m = 0; m < 4; ++m) a[m] = *(const short8v*)&As[wr + m * 16 + fr][kk * 32 + fk];
#pragma unroll
        for (int n = 0; n < 2; ++n) b[n] = *(const short8v*)&Bs[wc + n * 16 + fr][kk * 32 + fk];
#pragma unroll
        for (int m = 0; m < 4; ++m)
#pragma unroll
            for (int n = 0; n < 2; ++n)
                acc[m][n] = __builtin_amdgcn_mfma_f32_16x16x32_bf16(a[m], b[n], acc[m][n], 0, 0, 0);
    }
    __syncthreads();
    float (*stage)[68] = (float(*)[68])&As[0][0];
    int orow = (lane >> 4) * 4;
#pragma unroll
    for (int m = 0; m < 4; ++m)
#pragma unroll
        for (int n = 0; n < 2; ++n) {
            int col = wc + n * 16 + fr;
            float bv = bias[n0 + col];
#pragma unroll
            for (int j = 0; j < 4; ++j)
                stage[wr + m * 16 + orow + j][col] = acc[m][n][j] + bv;
        }
    __syncthreads();
#pragma unroll
    for (int u = 0; u < 8; ++u) {
        int idx = t + u * 256;
        int r = idx >> 4, c4 = idx & 15;
        *(float4*)&out[(size_t)(row0 + r) * 128 + n0 + c4 * 4] = *(const float4*)&stage[r][c4 * 4];
    }
}

// ---------------- histogram: cnt[e1], cnt2[n2] ----------------
__global__ void hist_kernel(const int* __restrict__ eei, const int* __restrict__ ei,
                            int* __restrict__ cnt, int* __restrict__ cnt2) {
    int p = blockIdx.x * 256 + threadIdx.x;
    int e0 = eei[p], e1 = eei[NEE + p];
    atomicAdd(&cnt[e1], 1);
    atomicAdd(&cnt2[ei[e0]], 1);
}

// ---------------- exclusive scan of cnt[32768] ----------------
__global__ void scan_kernel(const int* __restrict__ cnt, int* __restrict__ offs,
                            int* __restrict__ cursor) {
    __shared__ int part[1024];
    int t = threadIdx.x;
    int loc[32];
    int s = 0;
#pragma unroll
    for (int j = 0; j < 32; ++j) { loc[j] = cnt[t * 32 + j]; s += loc[j]; }
    part[t] = s;
    __syncthreads();
    for (int d = 1; d < 1024; d <<= 1) {
        int add = (t >= d) ? part[t - d] : 0;
        __syncthreads();
        part[t] += add;
        __syncthreads();
    }
    int excl = (t == 0) ? 0 : part[t - 1];
#pragma unroll
    for (int j = 0; j < 32; ++j) {
        offs[t * 32 + j] = excl;
        cursor[t * 32 + j] = excl;
        excl += loc[j];
    }
    if (t == 1023) offs[NE] = excl;
}

// ---------------- exclusive scan of cnt2[1024] ----------------
__global__ void scan2_kernel(const int* __restrict__ cnt2, int* __restrict__ offs2,
                             int* __restrict__ cursor2) {
    __shared__ int part[256];
    int t = threadIdx.x;
    int loc[4];
    int s = 0;
#pragma unroll
    for (int j = 0; j < 4; ++j) { loc[j] = cnt2[t * 4 + j]; s += loc[j]; }
    part[t] = s;
    __syncthreads();
    for (int d = 1; d < 256; d <<= 1) {
        int add = (t >= d) ? part[t - d] : 0;
        __syncthreads();
        part[t] += add;
        __syncthreads();
    }
    int excl = (t == 0) ? 0 : part[t - 1];
#pragma unroll
    for (int j = 0; j < 4; ++j) {
        offs2[t * 4 + j] = excl;
        cursor2[t * 4 + j] = excl;
        excl += loc[j];
    }
    if (t == 255) offs2[1024] = excl;
}

// ---------------- scatter: both CSRs + per-rank n1 and dist (kills bias's gather chain) ----------------
__global__ void scatter_both_kernel(const int* __restrict__ eei, const int* __restrict__ ei,
                                    const float* __restrict__ ntr,
                                    int* __restrict__ cursor, int* __restrict__ csr,
                                    int* __restrict__ cursor2, int* __restrict__ csr2,
                                    int* __restrict__ n1rank, float* __restrict__ drank) {
    int p = blockIdx.x * 256 + threadIdx.x;
    int e0 = eei[p], e1 = eei[NEE + p];
    int pos = atomicAdd(&cursor[e1], 1);
    csr[pos] = p;
    int n1 = ei[e1], n2 = ei[e0];
    int pos2 = atomicAdd(&cursor2[n2], 1);
    csr2[pos2] = p;
    n1rank[pos2] = n1;
    float dx = ntr[n1 * 3 + 0] - ntr[n2 * 3 + 0] + 1e-8f;
    float dy = ntr[n1 * 3 + 1] - ntr[n2 * 3 + 1] + 1e-8f;
    float dz = ntr[n1 * 3 + 2] - ntr[n2 * 3 + 2] + 1e-8f;
    drank[pos2] = sqrtf(dx * dx + dy * dy + dz * dz);
}

// ---------------- bias kernel: quarter-bucket MFMA blocks; scatter bias_p[p,4] ----------------
#define BSPLIT 4
__global__ void __launch_bounds__(256) bias_kernel(
    const int* __restrict__ csr2, const int* __restrict__ offs2,
    const int* __restrict__ n1rank, const float* __restrict__ drank,
    const ushort_t* __restrict__ nl16, const ushort_t* __restrict__ Tbf,
    const ushort_t* __restrict__ WdbT,
    const float* __restrict__ bbg, const float* __restrict__ bdb,
    const float* __restrict__ Wtb, float* __restrict__ bias_p) {
    __shared__ ushort_t Tt[128 * 24];   // [c][16 pad 24]
    __shared__ ushort_t Wd[128 * 72];   // [c][64 pad 72]
    int t = threadIdx.x;
    int n2 = blockIdx.x >> 2;
    int s  = blockIdx.x & 3;
    {
        const ushort_t* src = Tbf + n2 * 2048;
        int c = t >> 1, hh = t & 1;
        *(int4*)&Tt[c * 24 + hh * 8] = *(const int4*)&src[c * 16 + hh * 8];
    }
#pragma unroll
    for (int u = 0; u < 4; ++u) {
        int idx = t + u * 256;
        int c = idx >> 3, seg = idx & 7;
        *(int4*)&Wd[c * 72 + seg * 8] = *(const int4*)&WdbT[c * 64 + seg * 8];
    }
    __syncthreads();

    int lane = t & 63, w = t >> 6;
    int cl = lane & 15, g = lane >> 4;
    float wtb[8][4], bdbl[8], bbgl[8];
#pragma unroll
    for (int nb = 0; nb < 8; ++nb) {
        int c = nb * 16 + cl;
        float4 wt = *(const float4*)&Wtb[c * 4];
        wtb[nb][0] = wt.x; wtb[nb][1] = wt.y; wtb[nb][2] = wt.z; wtb[nb][3] = wt.w;
        bdbl[nb] = bdb[c];
        bbgl[nb] = bbg[c];
    }
    int bstart = offs2[n2], bend = offs2[n2 + 1];
    const float MU = 20.0f / 63.0f;

    for (int base = bstart + (s * 4 + w) * 16; base < bend; base += 16 * 4 * BSPLIT) {
        int idx = base + cl;
        int ip = (idx < bend) ? idx : (bend - 1);
        int n1 = n1rank[ip];          // coalesced
        float d = drank[ip];          // coalesced
        short8v aNL = {0, 0, 0, 0, 0, 0, 0, 0};
        if (g < 2) aNL = *(const short8v*)&nl16[n1 * 16 + g * 8];
        short8v ea, eb;
#pragma unroll
        for (int j = 0; j < 8; ++j) {
            float r = (float)(g * 8 + j);
            float t0 = (d - r * MU) * 3.2f;
            float t1 = (d - (r + 32.0f) * MU) * 3.2f;
            ea[j] = (short)f2bf(__expf(-t0 * t0));
            eb[j] = (short)f2bf(__expf(-t1 * t1));
        }
        float bacc[4][4] = {};
        f32x4 zero4 = {0.f, 0.f, 0.f, 0.f};
#pragma unroll
        for (int nb = 0; nb < 8; ++nb) {
            int c = nb * 16 + cl;
            short8v bT = {0, 0, 0, 0, 0, 0, 0, 0};
            if (g < 2) bT = *(const short8v*)&Tt[c * 24 + g * 8];
            f32x4 G = __builtin_amdgcn_mfma_f32_16x16x32_bf16(aNL, bT, zero4, 0, 0, 0);
            short8v bW0 = *(const short8v*)&Wd[c * 72 + g * 8];
            short8v bW1 = *(const short8v*)&Wd[c * 72 + 32 + g * 8];
            f32x4 D = __builtin_amdgcn_mfma_f32_16x16x32_bf16(ea, bW0, zero4, 0, 0, 0);
            D = __builtin_amdgcn_mfma_f32_16x16x32_bf16(eb, bW1, D, 0, 0, 0);
#pragma unroll
            for (int j = 0; j < 4; ++j) {
                float gv = G[j] + bbgl[nb];
                float db = D[j] + bdbl[nb];
                float sg = db * sigmoidf_(gv);
                bacc[j][0] += sg * wtb[nb][0];
                bacc[j][1] += sg * wtb[nb][1];
                bacc[j][2] += sg * wtb[nb][2];
                bacc[j][3] += sg * wtb[nb][3];
            }
        }
#pragma unroll
        for (int j = 0; j < 4; ++j)
#pragma unroll
            for (int h = 0; h < 4; ++h) {
                float v = bacc[j][h];
                v += __shfl_xor(v, 1);
                v += __shfl_xor(v, 2);
                v += __shfl_xor(v, 4);
                v += __shfl_xor(v, 8);
                bacc[j][h] = v;
            }
        int row = g * 4 + (cl >> 2), h = cl & 3;
        int oidx = base + row;
        if (oidx < bend) {
            int pp = csr2[oidx];
            bias_p[pp * 4 + h] = bacc[cl >> 2][h];
        }
    }
}

// ---------------- fused per-segment: qk, exp+bias, softmax-normalize, V, out-gate -> updg ----------------
// lane l owns columns c = 2l, 2l+1; head h = l>>4 (c>>5). packed uint loads.
__global__ void __launch_bounds__(256) segment_kernel(const ushort_t* __restrict__ qog,
                                                      const ushort_t* __restrict__ kv,
                                                      const float* __restrict__ bias_p,
                                                      const int* __restrict__ offs,
                                                      const int* __restrict__ csr,
                                                      const int* __restrict__ eei,
                                                      float* __restrict__ updg) {
    int t = threadIdx.x, wave = t >> 6, lane = t & 63;
    int gw = blockIdx.x * 4 + wave;
    int h = lane >> 4;
    const float scale = 0.08838834764831845f;  // 1/sqrt(128)
    for (int it = 0; it < 4; ++it) {
        int e = gw * 4 + it;
        int st = offs[e], en = offs[e + 1];
        unsigned qw = *(const unsigned*)&qog[(size_t)e * 256 + 2 * lane];
        float q0 = bf2f((ushort_t)(qw & 0xffff)), q1 = bf2f((ushort_t)(qw >> 16));
        float s = 0.f, u0 = 0.f, u1 = 0.f;
        for (int idx = st; idx < en; ++idx) {
            int p = csr[idx];
            int e0 = eei[p];
            const ushort_t* kvr = kv + (size_t)e0 * 256;
            unsigned kw = *(const unsigned*)&kvr[2 * lane];
            unsigned vw = *(const unsigned*)&kvr[128 + 2 * lane];
            float ta = q0 * bf2f((ushort_t)(kw & 0xffff)) + q1 * bf2f((ushort_t)(kw >> 16));
#pragma unroll
            for (int m = 1; m < 16; m <<= 1) ta += __shfl_xor(ta, m);
            float wgt = __expf(ta * scale + bias_p[p * 4 + h]);
            s += wgt;
            u0 += wgt * bf2f((ushort_t)(vw & 0xffff));
            u1 += wgt * bf2f((ushort_t)(vw >> 16));
        }
        float inv = 1.0f / (s + 1e-16f);
        unsigned ogw = *(const unsigned*)&qog[(size_t)e * 256 + 128 + 2 * lane];
        u0 = u0 * inv * sigmoidf_(bf2f((ushort_t)(ogw & 0xffff)));
        u1 = u1 * inv * sigmoidf_(bf2f((ushort_t)(ogw >> 16)));
        float2 uo; uo.x = u0; uo.y = u1;
        *(float2*)&updg[(size_t)e * 128 + 2 * lane] = uo;
    }
}

extern "C" void kernel_launch(void* const* d_in, const int* in_sizes, int n_in,
                              void* d_out, int out_size, void* d_ws, size_t ws_size,
                              hipStream_t stream) {
    const float* node_features = (const float*)d_in[0];
    const float* node_trans   = (const float*)d_in[1];
    const float* edge_features= (const float*)d_in[2];
    const int*   edge_index   = (const int*)d_in[3];
    const int*   eei          = (const int*)d_in[4];
    const float* ln_g  = (const float*)d_in[5];
    const float* ln_b  = (const float*)d_in[6];
    const float* W_nl  = (const float*)d_in[7];
    const float* b_nl  = (const float*)d_in[8];
    const float* W_nr  = (const float*)d_in[9];
    const float* b_nr  = (const float*)d_in[10];
    const float* W_bg  = (const float*)d_in[11];
    const float* b_bg  = (const float*)d_in[12];
    const float* W_db  = (const float*)d_in[13];
    const float* b_db  = (const float*)d_in[14];
    const float* W_tb  = (const float*)d_in[15];
    const float* W_q   = (const float*)d_in[16];
    const float* b_q   = (const float*)d_in[17];
    const float* W_kv  = (const float*)d_in[18];
    const float* b_kv  = (const float*)d_in[19];
    const float* W_og  = (const float*)d_in[20];
    const float* b_og  = (const float*)d_in[21];
    const float* W_out = (const float*)d_in[22];
    const float* b_out = (const float*)d_in[23];
    float* out = (float*)d_out;

    char* ws = (char*)d_ws;
    size_t off = 0;
    auto alloc = [&](size_t bytes) -> void* {
        void* p = ws + off;
        off += (bytes + 255) & ~(size_t)255;
        return p;
    };
    ushort_t* nl16  = (ushort_t*)alloc((size_t)NN * 16 * 2);
    float*    nr    = (float*)alloc((size_t)NN * 16 * 4);
    ushort_t* Tbf   = (ushort_t*)alloc((size_t)NN * 2048 * 2);
    ushort_t* WdbT  = (ushort_t*)alloc((size_t)128 * 64 * 2);
    ushort_t* WcatT = (ushort_t*)alloc((size_t)512 * 128 * 2);
    float*    bcat  = (float*)alloc((size_t)512 * 4);
    ushort_t* WoutT = (ushort_t*)alloc((size_t)128 * 128 * 2);
    ushort_t* ef_bf = (ushort_t*)alloc((size_t)NE * 128 * 2);
    ushort_t* qog   = (ushort_t*)alloc((size_t)NE * 256 * 2);
    ushort_t* kvb   = (ushort_t*)alloc((size_t)NE * 256 * 2);
    float*    bias_p= (float*)alloc((size_t)NEE * 4 * 4);
    float*    updg  = (float*)alloc((size_t)NE * 128 * 4);
    int*      cnt   = (int*)alloc((size_t)NE * 4);
    int*      cnt2  = (int*)alloc((size_t)1024 * 4);
    int*      offs  = (int*)alloc((size_t)(NE + 1) * 4);
    int*      offs2 = (int*)alloc((size_t)1025 * 4);
    int*      cursor  = (int*)alloc((size_t)NE * 4);
    int*      cursor2 = (int*)alloc((size_t)1024 * 4);
    int*      csr   = (int*)alloc((size_t)NEE * 4);
    int*      csr2  = (int*)alloc((size_t)NEE * 4);
    int*      n1rank= (int*)alloc((size_t)NEE * 4);
    float*    drank = (float*)alloc((size_t)NEE * 4);

    hipMemsetAsync(cnt, 0, (size_t)NE * 4 + 1024 * 4, stream);  // cnt + cnt2 contiguous

    node_proj_kernel<<<NN / 4, 256, 0, stream>>>(node_features, W_nl, b_nl, W_nr, b_nr, nl16, nr);
    build_Tt_kernel<<<NN, 256, 0, stream>>>(nr, W_bg, Tbf);
    ln_kernel<<<NE / 4, 256, 0, stream>>>(edge_features, ln_g, ln_b, ef_bf);
    prep_w_kernel<<<256, 256, 0, stream>>>(W_q, b_q, W_kv, b_kv, W_og, b_og, W_db, W_out,
                                           WcatT, bcat, WdbT, WoutT);
    mfma_gemm_proj<<<dim3(8, 256), 256, 0, stream>>>(ef_bf, WcatT, bcat, qog, kvb);
    hist_kernel<<<NEE / 256, 256, 0, stream>>>(eei, edge_index, cnt, cnt2);
    scan_kernel<<<1, 1024, 0, stream>>>(cnt, offs, cursor);
    scan2_kernel<<<1, 256, 0, stream>>>(cnt2, offs2, cursor2);
    scatter_both_kernel<<<NEE / 256, 256, 0, stream>>>(eei, edge_index, node_trans,
                                                       cursor, csr, cursor2, csr2, n1rank, drank);
    bias_kernel<<<NN * BSPLIT, 256, 0, stream>>>(csr2, offs2, n1rank, drank, nl16, Tbf, WdbT,
                                                 b_bg, b_db, W_tb, bias_p);
    segment_kernel<<<NE / 16, 256, 0, stream>>>(qog, kvb, bias_p, offs, csr, eei, updg);
    mfma_gemm_out<<<dim3(2, 256), 256, 0, stream>>>(updg, WoutT, b_out, out);
}

// Round 7
// 441.075 us; speedup vs baseline: 1.0253x; 1.0253x over previous
//
#include <hip/hip_runtime.h>
#include <math.h>

#define NN 1024
#define NE 32768
#define NEE 262144
#define CS 384
#define CZ 128
#define CG 16
#define NH 4
#define NR 64

typedef __attribute__((ext_vector_type(8))) short short8v;
typedef __attribute__((ext_vector_type(4))) float f32x4;
typedef unsigned short ushort_t;

__device__ __forceinline__ float sigmoidf_(float x) { return 1.0f / (1.0f + __expf(-x)); }

__device__ __forceinline__ ushort_t f2bf(float x) {
    union { float f; unsigned u; } v; v.f = x;
    unsigned r = v.u + 0x7fff + ((v.u >> 16) & 1);
    return (ushort_t)(r >> 16);
}
__device__ __forceinline__ float bf2f(ushort_t x) {
    union { unsigned u; float f; } v; v.u = ((unsigned)x) << 16;
    return v.f;
}

// ---------------- node projections: nl16 (bf16) [N,16], nr (f32) [N,16] ----------------
__global__ void node_proj_kernel(const float* __restrict__ nf,
                                 const float* __restrict__ Wl, const float* __restrict__ bl,
                                 const float* __restrict__ Wr, const float* __restrict__ br,
                                 ushort_t* __restrict__ nl16, float* __restrict__ nr) {
    int wave = threadIdx.x >> 6, lane = threadIdx.x & 63;
    int n = blockIdx.x * 4 + wave;
    if (lane >= 32) return;
    bool isl = lane < 16;
    int o = isl ? lane : lane - 16;
    const float* W = isl ? Wl : Wr;
    float acc = isl ? bl[o] : br[o];
    const float* x = nf + n * CS;
    for (int k = 0; k < CS; ++k) acc += x[k] * W[k * 16 + o];
    if (isl) nl16[n * 16 + o] = f2bf(acc);
    else     nr[n * 16 + o] = acc;
}

// ---------------- Tbf[n][c][i] (bf16) = sum_j nr[n,j]*W_bg[(16i+j),c] ----------------
__global__ void build_Tt_kernel(const float* __restrict__ nr, const float* __restrict__ Wbg,
                                ushort_t* __restrict__ Tbf) {
    int n = blockIdx.x;
    int t = threadIdx.x;
    int c = t & 127, i0 = t >> 7;
    __shared__ float nrs[16];
    if (t < 16) nrs[t] = nr[n * 16 + t];
    __syncthreads();
    for (int i = i0; i < 16; i += 2) {
        float acc = 0.f;
#pragma unroll
        for (int j = 0; j < 16; ++j) acc += nrs[j] * Wbg[(i * 16 + j) * 128 + c];
        Tbf[n * 2048 + c * 16 + i] = f2bf(acc);
    }
}

// ---------------- LayerNorm over 128 -> bf16 ----------------
__global__ void ln_kernel(const float* __restrict__ x, const float* __restrict__ g,
                          const float* __restrict__ b, ushort_t* __restrict__ ef) {
    int wave = threadIdx.x >> 6, lane = threadIdx.x & 63;
    int e = blockIdx.x * 4 + wave;
    int c0 = lane, c1 = lane + 64;
    float x0 = x[e * 128 + c0], x1 = x[e * 128 + c1];
    float s = x0 + x1;
#pragma unroll
    for (int m = 1; m < 64; m <<= 1) s += __shfl_xor(s, m);
    float mean = s * (1.f / 128.f);
    float d0 = x0 - mean, d1 = x1 - mean;
    float v = d0 * d0 + d1 * d1;
#pragma unroll
    for (int m = 1; m < 64; m <<= 1) v += __shfl_xor(v, m);
    v *= (1.f / 128.f);
    float inv = rsqrtf(v + 1e-5f);
    ef[e * 128 + c0] = f2bf(d0 * inv * g[c0] + b[c0]);
    ef[e * 128 + c1] = f2bf(d1 * inv * g[c1] + b[c1]);
}

// ---------------- prep weights: WcatT(bf16, col order q|og|k|v), bcat, WdbT, WoutT ----------------
__global__ void prep_w_kernel(const float* __restrict__ Wq, const float* __restrict__ bq,
                              const float* __restrict__ Wkv, const float* __restrict__ bkv,
                              const float* __restrict__ Wog, const float* __restrict__ bog,
                              const float* __restrict__ Wdb, const float* __restrict__ Wout,
                              ushort_t* __restrict__ WcatT, float* __restrict__ bcat,
                              ushort_t* __restrict__ WdbT, ushort_t* __restrict__ WoutT) {
    int idx = blockIdx.x * 256 + threadIdx.x;  // 65536 total
    int col = idx >> 7, k = idx & 127;
    float w;
    if (col < 128) w = Wq[k * 128 + col];
    else if (col < 256) w = Wog[k * 128 + (col - 128)];
    else if (col < 384) w = Wkv[k * 256 + (col - 256)];
    else w = Wkv[k * 256 + 128 + (col - 384)];
    WcatT[idx] = f2bf(w);
    if (idx < 512) {
        float bb;
        if (idx < 128) bb = bq[idx];
        else if (idx < 256) bb = bog[idx - 128];
        else if (idx < 384) bb = bkv[idx - 256];
        else bb = bkv[idx - 384 + 128];
        bcat[idx] = bb;
    }
    if (idx < 128 * 64) {
        int c = idx >> 6, r = idx & 63;
        WdbT[idx] = f2bf(Wdb[r * 128 + c]);
    }
    if (idx < 128 * 128) {
        int c = idx >> 7, kk = idx & 127;
        WoutT[idx] = f2bf(Wout[kk * 128 + c]);
    }
}

// ---------------- MFMA GEMM: [32768,128]bf16 @ [128,512] -> qog[E,256]bf16, kv[E,256]bf16 ----------------
__global__ void __launch_bounds__(256) mfma_gemm_proj(const ushort_t* __restrict__ Abf,
                                                      const ushort_t* __restrict__ Bt,
                                                      const float* __restrict__ bias,
                                                      ushort_t* __restrict__ qog,
                                                      ushort_t* __restrict__ kvo) {
    __shared__ ushort_t As[128][136];
    __shared__ ushort_t Bs[64][136];
    int t = threadIdx.x;
    int row0 = blockIdx.y * 128;
    int n0 = blockIdx.x * 64;
#pragma unroll
    for (int u = 0; u < 8; ++u) {
        int idx = t + u * 256;
        int r = idx >> 4, seg = idx & 15;
        *(short8v*)&As[r][seg * 8] = *(const short8v*)&Abf[(size_t)(row0 + r) * 128 + seg * 8];
    }
#pragma unroll
    for (int u = 0; u < 4; ++u) {
        int idx = t + u * 256;
        int r = idx >> 4, seg = idx & 15;
        *(short8v*)&Bs[r][seg * 8] = *(const short8v*)&Bt[(size_t)(n0 + r) * 128 + seg * 8];
    }
    __syncthreads();
    int lane = t & 63, w = t >> 6;
    int wr = (w >> 1) * 64, wc = (w & 1) * 32;
    int fr = lane & 15, fk = (lane >> 4) * 8;
    f32x4 acc[4][2] = {};
#pragma unroll
    for (int kk = 0; kk < 4; ++kk) {
        short8v a[4], b[2];
#pragma unroll
        for (int m = 0; m < 4; ++m) a[m] = *(const short8v*)&As[wr + m * 16 + fr][kk * 32 + fk];
#pragma unroll
        for (int n = 0; n < 2; ++n) b[n] = *(const short8v*)&Bs[wc + n * 16 + fr][kk * 32 + fk];
#pragma unroll
        for (int m = 0; m < 4; ++m)
#pragma unroll
            for (int n = 0; n < 2; ++n)
                acc[m][n] = __builtin_amdgcn_mfma_f32_16x16x32_bf16(a[m], b[n], acc[m][n], 0, 0, 0);
    }
    __syncthreads();
    ushort_t (*stage)[72] = (ushort_t(*)[72])&As[0][0];
    int orow = (lane >> 4) * 4;
#pragma unroll
    for (int m = 0; m < 4; ++m)
#pragma unroll
        for (int n = 0; n < 2; ++n) {
            int col = wc + n * 16 + fr;
            float bv = bias[n0 + col];
#pragma unroll
            for (int j = 0; j < 4; ++j)
                stage[wr + m * 16 + orow + j][col] = f2bf(acc[m][n][j] + bv);
        }
    __syncthreads();
    ushort_t* basep; int cbase;
    if (n0 < 256) { basep = qog; cbase = n0; } else { basep = kvo; cbase = n0 - 256; }
#pragma unroll
    for (int u = 0; u < 4; ++u) {
        int idx = t + u * 256;
        int r = idx >> 3, seg = idx & 7;
        *(short8v*)&basep[(size_t)(row0 + r) * 256 + cbase + seg * 8] = *(const short8v*)&stage[r][seg * 8];
    }
}

// ---------------- MFMA GEMM: out[32768,128]f32 = updg(f32->bf16) @ WoutT + b_out ----------------
__global__ void __launch_bounds__(256) mfma_gemm_out(const float* __restrict__ Af,
                                                     const ushort_t* __restrict__ Bt,
                                                     const float* __restrict__ bias,
                                                     float* __restrict__ out) {
    __shared__ ushort_t As[128][136];
    __shared__ ushort_t Bs[64][136];
    int t = threadIdx.x;
    int row0 = blockIdx.y * 128;
    int n0 = blockIdx.x * 64;
#pragma unroll
    for (int u = 0; u < 8; ++u) {
        int idx = t + u * 256;
        int r = idx >> 4, seg = idx & 15;
        float4 f0 = *(const float4*)&Af[(size_t)(row0 + r) * 128 + seg * 8];
        float4 f1 = *(const float4*)&Af[(size_t)(row0 + r) * 128 + seg * 8 + 4];
        short8v pk;
        pk[0] = (short)f2bf(f0.x); pk[1] = (short)f2bf(f0.y);
        pk[2] = (short)f2bf(f0.z); pk[3] = (short)f2bf(f0.w);
        pk[4] = (short)f2bf(f1.x); pk[5] = (short)f2bf(f1.y);
        pk[6] = (short)f2bf(f1.z); pk[7] = (short)f2bf(f1.w);
        *(short8v*)&As[r][seg * 8] = pk;
    }
#pragma unroll
    for (int u = 0; u < 4; ++u) {
        int idx = t + u * 256;
        int r = idx >> 4, seg = idx & 15;
        *(short8v*)&Bs[r][seg * 8] = *(const short8v*)&Bt[(size_t)(n0 + r) * 128 + seg * 8];
    }
    __syncthreads();
    int lane = t & 63, w = t >> 6;
    int wr = (w >> 1) * 64, wc = (w & 1) * 32;
    int fr = lane & 15, fk = (lane >> 4) * 8;
    f32x4 acc[4][2] = {};
#pragma unroll
    for (int kk = 0; kk < 4; ++kk) {
        short8v a[4], b[2];
#pragma unroll
        for (int m = 0; m < 4; ++m) a[m] = *(const short8v*)&As[wr + m * 16 + fr][kk * 32 + fk];
#pragma unroll
        for (int n = 0; n < 2; ++n) b[n] = *(const short8v*)&Bs[wc + n * 16 + fr][kk * 32 + fk];
#pragma unroll
        for (int m = 0; m < 4; ++m)
#pragma unroll
            for (int n = 0; n < 2; ++n)
                acc[m][n] = __builtin_amdgcn_mfma_f32_16x16x32_bf16(a[m], b[n], acc[m][n], 0, 0, 0);
    }
    __syncthreads();
    float (*stage)[68] = (float(*)[68])&As[0][0];
    int orow = (lane >> 4) * 4;
#pragma unroll
    for (int m = 0; m < 4; ++m)
#pragma unroll
        for (int n = 0; n < 2; ++n) {
            int col = wc + n * 16 + fr;
            float bv = bias[n0 + col];
#pragma unroll
            for (int j = 0; j < 4; ++j)
                stage[wr + m * 16 + orow + j][col] = acc[m][n][j] + bv;
        }
    __syncthreads();
#pragma unroll
    for (int u = 0; u < 8; ++u) {
        int idx = t + u * 256;
        int r = idx >> 4, c4 = idx & 15;
        *(float4*)&out[(size_t)(row0 + r) * 128 + n0 + c4 * 4] = *(const float4*)&stage[r][c4 * 4];
    }
}

// ---------------- histogram: cnt[e1], cnt2[n2] ----------------
__global__ void hist_kernel(const int* __restrict__ eei, const int* __restrict__ ei,
                            int* __restrict__ cnt, int* __restrict__ cnt2) {
    int p = blockIdx.x * 256 + threadIdx.x;
    int e0 = eei[p], e1 = eei[NEE + p];
    atomicAdd(&cnt[e1], 1);
    atomicAdd(&cnt2[ei[e0]], 1);
}

// ---------------- exclusive scan of cnt[32768] ----------------
__global__ void scan_kernel(const int* __restrict__ cnt, int* __restrict__ offs,
                            int* __restrict__ cursor) {
    __shared__ int part[1024];
    int t = threadIdx.x;
    int loc[32];
    int s = 0;
#pragma unroll
    for (int j = 0; j < 32; ++j) { loc[j] = cnt[t * 32 + j]; s += loc[j]; }
    part[t] = s;
    __syncthreads();
    for (int d = 1; d < 1024; d <<= 1) {
        int add = (t >= d) ? part[t - d] : 0;
        __syncthreads();
        part[t] += add;
        __syncthreads();
    }
    int excl = (t == 0) ? 0 : part[t - 1];
#pragma unroll
    for (int j = 0; j < 32; ++j) {
        offs[t * 32 + j] = excl;
        cursor[t * 32 + j] = excl;
        excl += loc[j];
    }
    if (t == 1023) offs[NE] = excl;
}

// ---------------- exclusive scan of cnt2[1024] ----------------
__global__ void scan2_kernel(const int* __restrict__ cnt2, int* __restrict__ offs2,
                             int* __restrict__ cursor2) {
    __shared__ int part[256];
    int t = threadIdx.x;
    int loc[4];
    int s = 0;
#pragma unroll
    for (int j = 0; j < 4; ++j) { loc[j] = cnt2[t * 4 + j]; s += loc[j]; }
    part[t] = s;
    __syncthreads();
    for (int d = 1; d < 256; d <<= 1) {
        int add = (t >= d) ? part[t - d] : 0;
        __syncthreads();
        part[t] += add;
        __syncthreads();
    }
    int excl = (t == 0) ? 0 : part[t - 1];
#pragma unroll
    for (int j = 0; j < 4; ++j) {
        offs2[t * 4 + j] = excl;
        cursor2[t * 4 + j] = excl;
        excl += loc[j];
    }
    if (t == 255) offs2[1024] = excl;
}

// ---------------- scatter: e0 in e1-CSR order; n1/dist/rank-map in n2-CSR order ----------------
__global__ void scatter_both_kernel(const int* __restrict__ eei, const int* __restrict__ ei,
                                    const float* __restrict__ ntr,
                                    int* __restrict__ cursor, int* __restrict__ e0rank,
                                    int* __restrict__ cursor2, int* __restrict__ n1rank,
                                    float* __restrict__ drank, int* __restrict__ x2to1) {
    int p = blockIdx.x * 256 + threadIdx.x;
    int e0 = eei[p], e1 = eei[NEE + p];
    int pos = atomicAdd(&cursor[e1], 1);
    e0rank[pos] = e0;
    int n1 = ei[e1], n2 = ei[e0];
    int pos2 = atomicAdd(&cursor2[n2], 1);
    n1rank[pos2] = n1;
    x2to1[pos2] = pos;
    float dx = ntr[n1 * 3 + 0] - ntr[n2 * 3 + 0] + 1e-8f;
    float dy = ntr[n1 * 3 + 1] - ntr[n2 * 3 + 1] + 1e-8f;
    float dz = ntr[n1 * 3 + 2] - ntr[n2 * 3 + 2] + 1e-8f;
    drank[pos2] = sqrtf(dx * dx + dy * dy + dz * dz);
}

// ---------------- bias kernel: per-n2-bucket, batched MFMA phases; writes bias in e1-CSR order ----------------
__global__ void __launch_bounds__(256) bias_kernel(
    const int* __restrict__ offs2, const int* __restrict__ n1rank,
    const float* __restrict__ drank, const int* __restrict__ x2to1,
    const ushort_t* __restrict__ nl16, const ushort_t* __restrict__ Tbf,
    const ushort_t* __restrict__ WdbT,
    const float* __restrict__ bbg, const float* __restrict__ bdb,
    const float* __restrict__ Wtb, float* __restrict__ bias_cs) {
    __shared__ ushort_t Tt[128 * 24];   // [c][16 pad 24]
    __shared__ ushort_t Wd[128 * 72];   // [c][64 pad 72]
    int t = threadIdx.x;
    int n2 = blockIdx.x;
    {
        const ushort_t* src = Tbf + n2 * 2048;
        int c = t >> 1, hh = t & 1;
        *(int4*)&Tt[c * 24 + hh * 8] = *(const int4*)&src[c * 16 + hh * 8];
    }
#pragma unroll
    for (int u = 0; u < 4; ++u) {
        int idx = t + u * 256;
        int c = idx >> 3, seg = idx & 7;
        *(int4*)&Wd[c * 72 + seg * 8] = *(const int4*)&WdbT[c * 64 + seg * 8];
    }
    __syncthreads();

    int lane = t & 63, w = t >> 6;
    int cl = lane & 15, g = lane >> 4;
    float wtb[8][4], bdbl[8], bbgl[8];
#pragma unroll
    for (int nb = 0; nb < 8; ++nb) {
        int c = nb * 16 + cl;
        float4 wt = *(const float4*)&Wtb[c * 4];
        wtb[nb][0] = wt.x; wtb[nb][1] = wt.y; wtb[nb][2] = wt.z; wtb[nb][3] = wt.w;
        bdbl[nb] = bdb[c];
        bbgl[nb] = bbg[c];
    }
    int bstart = offs2[n2], bend = offs2[n2 + 1];
    const float MU = 20.0f / 63.0f;
    f32x4 zero4 = {0.f, 0.f, 0.f, 0.f};

    for (int base = bstart + w * 16; base < bend; base += 64) {
        int idx = base + cl;
        int ip = (idx < bend) ? idx : (bend - 1);
        int n1 = n1rank[ip];          // coalesced
        float d = drank[ip];          // coalesced
        short8v aNL = {0, 0, 0, 0, 0, 0, 0, 0};
        if (g < 2) aNL = *(const short8v*)&nl16[n1 * 16 + g * 8];
        short8v ea, eb;
#pragma unroll
        for (int j = 0; j < 8; ++j) {
            float r = (float)(g * 8 + j);
            float t0 = (d - r * MU) * 3.2f;
            float t1 = (d - (r + 32.0f) * MU) * 3.2f;
            ea[j] = (short)f2bf(__expf(-t0 * t0));
            eb[j] = (short)f2bf(__expf(-t1 * t1));
        }
        // phase 1: batch all gate-MFMA B-frags, issue 8 independent MFMAs
        f32x4 G[8], D[8];
#pragma unroll
        for (int nb = 0; nb < 8; ++nb) {
            short8v bT = {0, 0, 0, 0, 0, 0, 0, 0};
            if (g < 2) bT = *(const short8v*)&Tt[(nb * 16 + cl) * 24 + g * 8];
            G[nb] = __builtin_amdgcn_mfma_f32_16x16x32_bf16(aNL, bT, zero4, 0, 0, 0);
        }
        // phase 2: batch rbf-MFMA B-frags, 16 MFMAs (2 per nb, chained only pairwise)
#pragma unroll
        for (int nb = 0; nb < 8; ++nb) {
            short8v bW0 = *(const short8v*)&Wd[(nb * 16 + cl) * 72 + g * 8];
            short8v bW1 = *(const short8v*)&Wd[(nb * 16 + cl) * 72 + 32 + g * 8];
            f32x4 tmp = __builtin_amdgcn_mfma_f32_16x16x32_bf16(ea, bW0, zero4, 0, 0, 0);
            D[nb] = __builtin_amdgcn_mfma_f32_16x16x32_bf16(eb, bW1, tmp, 0, 0, 0);
        }
        // phase 3: VALU epilogue
        float bacc[4][4] = {};
#pragma unroll
        for (int nb = 0; nb < 8; ++nb) {
#pragma unroll
            for (int j = 0; j < 4; ++j) {
                float gv = G[nb][j] + bbgl[nb];
                float db = D[nb][j] + bdbl[nb];
                float sg = db * sigmoidf_(gv);
                bacc[j][0] += sg * wtb[nb][0];
                bacc[j][1] += sg * wtb[nb][1];
                bacc[j][2] += sg * wtb[nb][2];
                bacc[j][3] += sg * wtb[nb][3];
            }
        }
#pragma unroll
        for (int j = 0; j < 4; ++j)
#pragma unroll
            for (int h = 0; h < 4; ++h) {
                float v = bacc[j][h];
                v += __shfl_xor(v, 1);
                v += __shfl_xor(v, 2);
                v += __shfl_xor(v, 4);
                v += __shfl_xor(v, 8);
                bacc[j][h] = v;
            }
        int row = g * 4 + (cl >> 2), h = cl & 3;
        int oidx = base + row;
        if (oidx < bend) {
            int dst = x2to1[oidx];
            bias_cs[(size_t)dst * 4 + h] = bacc[cl >> 2][h];
        }
    }
}

// ---------------- fused per-segment: qk, exp+bias, softmax-normalize, V, out-gate -> updg ----------------
// lane l owns columns c = 2l, 2l+1; head h = l>>4. e0rank + bias_cs are rank-ordered (coalesced).
__global__ void __launch_bounds__(256) segment_kernel(const ushort_t* __restrict__ qog,
                                                      const ushort_t* __restrict__ kv,
                                                      const float* __restrict__ bias_cs,
                                                      const int* __restrict__ offs,
                                                      const int* __restrict__ e0rank,
                                                      float* __restrict__ updg) {
    int t = threadIdx.x, wave = t >> 6, lane = t & 63;
    int gw = blockIdx.x * 4 + wave;
    int h = lane >> 4;
    const float scale = 0.08838834764831845f;  // 1/sqrt(128)
    for (int it = 0; it < 4; ++it) {
        int e = gw * 4 + it;
        int st = offs[e], en = offs[e + 1];
        unsigned qw = *(const unsigned*)&qog[(size_t)e * 256 + 2 * lane];
        float q0 = bf2f((ushort_t)(qw & 0xffff)), q1 = bf2f((ushort_t)(qw >> 16));
        float s = 0.f, u0 = 0.f, u1 = 0.f;
        for (int idx = st; idx < en; ++idx) {
            int e0 = e0rank[idx];                 // uniform scalar load
            const ushort_t* kvr = kv + (size_t)e0 * 256;
            unsigned kw = *(const unsigned*)&kvr[2 * lane];
            unsigned vw = *(const unsigned*)&kvr[128 + 2 * lane];
            float ta = q0 * bf2f((ushort_t)(kw & 0xffff)) + q1 * bf2f((ushort_t)(kw >> 16));
#pragma unroll
            for (int m = 1; m < 16; m <<= 1) ta += __shfl_xor(ta, m);
            float wgt = __expf(ta * scale + bias_cs[(size_t)idx * 4 + h]);
            s += wgt;
            u0 += wgt * bf2f((ushort_t)(vw & 0xffff));
            u1 += wgt * bf2f((ushort_t)(vw >> 16));
        }
        float inv = 1.0f / (s + 1e-16f);
        unsigned ogw = *(const unsigned*)&qog[(size_t)e * 256 + 128 + 2 * lane];
        u0 = u0 * inv * sigmoidf_(bf2f((ushort_t)(ogw & 0xffff)));
        u1 = u1 * inv * sigmoidf_(bf2f((ushort_t)(ogw >> 16)));
        float2 uo; uo.x = u0; uo.y = u1;
        *(float2*)&updg[(size_t)e * 128 + 2 * lane] = uo;
    }
}

extern "C" void kernel_launch(void* const* d_in, const int* in_sizes, int n_in,
                              void* d_out, int out_size, void* d_ws, size_t ws_size,
                              hipStream_t stream) {
    const float* node_features = (const float*)d_in[0];
    const float* node_trans   = (const float*)d_in[1];
    const float* edge_features= (const float*)d_in[2];
    const int*   edge_index   = (const int*)d_in[3];
    const int*   eei          = (const int*)d_in[4];
    const float* ln_g  = (const float*)d_in[5];
    const float* ln_b  = (const float*)d_in[6];
    const float* W_nl  = (const float*)d_in[7];
    const float* b_nl  = (const float*)d_in[8];
    const float* W_nr  = (const float*)d_in[9];
    const float* b_nr  = (const float*)d_in[10];
    const float* W_bg  = (const float*)d_in[11];
    const float* b_bg  = (const float*)d_in[12];
    const float* W_db  = (const float*)d_in[13];
    const float* b_db  = (const float*)d_in[14];
    const float* W_tb  = (const float*)d_in[15];
    const float* W_q   = (const float*)d_in[16];
    const float* b_q   = (const float*)d_in[17];
    const float* W_kv  = (const float*)d_in[18];
    const float* b_kv  = (const float*)d_in[19];
    const float* W_og  = (const float*)d_in[20];
    const float* b_og  = (const float*)d_in[21];
    const float* W_out = (const float*)d_in[22];
    const float* b_out = (const float*)d_in[23];
    float* out = (float*)d_out;

    char* ws = (char*)d_ws;
    size_t off = 0;
    auto alloc = [&](size_t bytes) -> void* {
        void* p = ws + off;
        off += (bytes + 255) & ~(size_t)255;
        return p;
    };
    ushort_t* nl16  = (ushort_t*)alloc((size_t)NN * 16 * 2);
    float*    nr    = (float*)alloc((size_t)NN * 16 * 4);
    ushort_t* Tbf   = (ushort_t*)alloc((size_t)NN * 2048 * 2);
    ushort_t* WdbT  = (ushort_t*)alloc((size_t)128 * 64 * 2);
    ushort_t* WcatT = (ushort_t*)alloc((size_t)512 * 128 * 2);
    float*    bcat  = (float*)alloc((size_t)512 * 4);
    ushort_t* WoutT = (ushort_t*)alloc((size_t)128 * 128 * 2);
    ushort_t* ef_bf = (ushort_t*)alloc((size_t)NE * 128 * 2);
    ushort_t* qog   = (ushort_t*)alloc((size_t)NE * 256 * 2);
    ushort_t* kvb   = (ushort_t*)alloc((size_t)NE * 256 * 2);
    float*    bias_cs = (float*)alloc((size_t)NEE * 4 * 4);
    float*    updg  = (float*)alloc((size_t)NE * 128 * 4);
    int*      cnt   = (int*)alloc((size_t)NE * 4);
    int*      cnt2  = (int*)alloc((size_t)1024 * 4);
    int*      offs  = (int*)alloc((size_t)(NE + 1) * 4);
    int*      offs2 = (int*)alloc((size_t)1025 * 4);
    int*      cursor  = (int*)alloc((size_t)NE * 4);
    int*      cursor2 = (int*)alloc((size_t)1024 * 4);
    int*      e0rank= (int*)alloc((size_t)NEE * 4);
    int*      n1rank= (int*)alloc((size_t)NEE * 4);
    float*    drank = (float*)alloc((size_t)NEE * 4);
    int*      x2to1 = (int*)alloc((size_t)NEE * 4);

    hipMemsetAsync(cnt, 0, (size_t)NE * 4 + 1024 * 4, stream);  // cnt + cnt2 contiguous

    node_proj_kernel<<<NN / 4, 256, 0, stream>>>(node_features, W_nl, b_nl, W_nr, b_nr, nl16, nr);
    build_Tt_kernel<<<NN, 256, 0, stream>>>(nr, W_bg, Tbf);
    ln_kernel<<<NE / 4, 256, 0, stream>>>(edge_features, ln_g, ln_b, ef_bf);
    prep_w_kernel<<<256, 256, 0, stream>>>(W_q, b_q, W_kv, b_kv, W_og, b_og, W_db, W_out,
                                           WcatT, bcat, WdbT, WoutT);
    mfma_gemm_proj<<<dim3(8, 256), 256, 0, stream>>>(ef_bf, WcatT, bcat, qog, kvb);
    hist_kernel<<<NEE / 256, 256, 0, stream>>>(eei, edge_index, cnt, cnt2);
    scan_kernel<<<1, 1024, 0, stream>>>(cnt, offs, cursor);
    scan2_kernel<<<1, 256, 0, stream>>>(cnt2, offs2, cursor2);
    scatter_both_kernel<<<NEE / 256, 256, 0, stream>>>(eei, edge_index, node_trans,
                                                       cursor, e0rank, cursor2, n1rank, drank, x2to1);
    bias_kernel<<<NN, 256, 0, stream>>>(offs2, n1rank, drank, x2to1, nl16, Tbf, WdbT,
                                        b_bg, b_db, W_tb, bias_cs);
    segment_kernel<<<NE / 16, 256, 0, stream>>>(qog, kvb, bias_cs, offs, e0rank, updg);
    mfma_gemm_out<<<dim3(2, 256), 256, 0, stream>>>(updg, WoutT, b_out, out);
}